// Round 6
// baseline (621.101 us; speedup 1.0000x reference)
//
#include <hip/hip_runtime.h>
#include <cstdint>

typedef unsigned short u16;
typedef __attribute__((ext_vector_type(8))) short short8;
typedef __attribute__((ext_vector_type(4))) float floatx4;

#define BAR()      __builtin_amdgcn_s_barrier()
#define SCHEDBAR() __builtin_amdgcn_sched_barrier(0)

__device__ __forceinline__ u16 f2bf(float f) {
    unsigned u = __float_as_uint(f);
    u += 0x7FFFu + ((u >> 16) & 1u);
    return (u16)(u >> 16);
}

__device__ __forceinline__ void async16(const void* g, void* l) {
    __builtin_amdgcn_global_load_lds(
        (const __attribute__((address_space(1))) unsigned*)g,
        (__attribute__((address_space(3))) unsigned*)l, 16, 0, 0);
}

// ---------------- cast fp32 -> bf16, 8 elems/thread ----------------
__global__ void cast_bf16_kernel(const float* __restrict__ in, u16* __restrict__ out, long n8) {
    long i = (long)blockIdx.x * 256 + threadIdx.x;
    if (i >= n8) return;
    const float4* p = (const float4*)in;
    float4 a = p[i * 2], b = p[i * 2 + 1];
    uint4 o;
    o.x = f2bf(a.x) | ((unsigned)f2bf(a.y) << 16);
    o.y = f2bf(a.z) | ((unsigned)f2bf(a.w) << 16);
    o.z = f2bf(b.x) | ((unsigned)f2bf(b.y) << 16);
    o.w = f2bf(b.z) | ((unsigned)f2bf(b.w) << 16);
    ((uint4*)out)[i] = o;
}

// ---------------- zero fill (uint4 granularity) ----------------
__global__ void fill_zero(uint4* __restrict__ p, int n) {
    int i = blockIdx.x * 256 + threadIdx.x;
    if (i < n) p[i] = (uint4){0u, 0u, 0u, 0u};
}

// ---------------- transpose + cast: W[K][N] -> Wt[N][K] bf16 ----------------
__global__ void transpose_cast(const float* __restrict__ W, u16* __restrict__ Wt, int K, int N) {
    __shared__ float tile[32][33];
    int bx = blockIdx.x * 32, by = blockIdx.y * 32;
    int tx = threadIdx.x, ty = threadIdx.y;
#pragma unroll
    for (int i = 0; i < 32; i += 8)
        tile[ty + i][tx] = W[(long)(by + ty + i) * N + bx + tx];
    __syncthreads();
#pragma unroll
    for (int i = 0; i < 32; i += 8)
        Wt[(long)(bx + ty + i) * K + by + tx] = f2bf(tile[tx][ty + i]);
}

// ---------------- gemm8p helpers ----------------
__device__ __forceinline__ void rd8(short8 (&a)[2][4], const u16* sm, int base, int g0, int g1) {
#pragma unroll
    for (int mi = 0; mi < 4; ++mi) {
        a[0][mi] = *(const short8*)&sm[base + mi * 1024 + g0];
        a[1][mi] = *(const short8*)&sm[base + mi * 1024 + g1];
    }
}
__device__ __forceinline__ void rd6(short8 (&b)[2][3], const u16* sm, int base, int g0, int g1) {
#pragma unroll
    for (int ni = 0; ni < 3; ++ni) {
        b[0][ni] = *(const short8*)&sm[base + ni * 1024 + g0];
        b[1][ni] = *(const short8*)&sm[base + ni * 1024 + g1];
    }
}
__device__ __forceinline__ void mfma24(floatx4 (&ah)[4][3], const short8 (&a)[2][4], const short8 (&b)[2][3]) {
#pragma unroll
    for (int kk = 0; kk < 2; ++kk)
#pragma unroll
        for (int mi = 0; mi < 4; ++mi)
#pragma unroll
            for (int ni = 0; ni < 3; ++ni)
                ah[mi][ni] = __builtin_amdgcn_mfma_f32_16x16x32_bf16(a[kk][mi], b[kk][ni], ah[mi][ni], 0, 0, 0);
}

// ============ 2-phase 256x192 GEMM (unchanged from R5) ============
template <int MODE>
__global__ __launch_bounds__(512, 2)
void gemm8p(const u16* __restrict__ A, const u16* __restrict__ Bt,
            const float* __restrict__ bias, float scale,
            u16* __restrict__ outA, float* __restrict__ outF) {
    extern __shared__ u16 smem[];   // u16 units: A bufs [0,32768); B bufs [32768,57344)
    const int K = 1152;
    const int tid = threadIdx.x, lane = tid & 63, wave = tid >> 6;
    const int quad = lane >> 4, cl = lane & 15;
    const int wm = wave >> 2, wn = wave & 3;
    const int l3 = lane >> 3, l7 = lane & 7;
    const int w8 = wave * 8;

    int bid = blockIdx.x;
    int swz = (bid & 7) * 96 + (bid >> 3);
    int colTile = swz % 6, rowTile = swz / 6;
    const long rowBase = (long)rowTile * 256;
    const int colBase = colTile * 192;

    const int sg = (l7 ^ l3) * 8;
    const u16* pA = A + (rowBase + l3) * (long)K + sg;
    const u16* pB = Bt + ((long)colBase + l3) * (long)K + sg;

    auto stA = [&](int Ts, int r0) {
        async16(pA + (long)r0 * K + Ts * 64, &smem[(Ts & 1) * 16384 + r0 * 64]);
    };
    auto stB = [&](int Ts, int r0) {
        async16(pB + (long)r0 * K + Ts * 64, &smem[32768 + (Ts & 1) * 12288 + r0 * 64]);
    };

    const int arow = wm * 8192 + cl * 64;
    const int brow = wn * 3072 + cl * 64;
    const int gs0 = (quad ^ (cl & 7)) * 8;
    const int gs1 = ((4 + quad) ^ (cl & 7)) * 8;

    floatx4 acc[2][4][3];
#pragma unroll
    for (int h = 0; h < 2; ++h)
#pragma unroll
        for (int i = 0; i < 4; ++i)
#pragma unroll
            for (int j = 0; j < 3; ++j) acc[h][i][j] = (floatx4){0.f, 0.f, 0.f, 0.f};

    short8 a0[2][4], a1[2][4], bf[2][3];

    stA(0, w8); stA(0, 128 + w8);
    stB(0, w8); stB(0, 64 + w8); stB(0, 128 + w8);
    stA(0, 64 + w8); stA(0, 192 + w8);
    stA(1, w8); stA(1, 128 + w8);
    stB(1, w8); stB(1, 64 + w8); stB(1, 128 + w8);
    SCHEDBAR();
    asm volatile("s_waitcnt vmcnt(7)");
    SCHEDBAR();
    BAR();

#pragma unroll 2
    for (int T = 0; T < 16; ++T) {
        const int ab = (T & 1) * 16384;
        const int bb = 32768 + (T & 1) * 12288;
        rd8(a0, smem, ab + arow, gs0, gs1);
        rd6(bf, smem, bb + brow, gs0, gs1);
        stA(T + 1, 64 + w8); stA(T + 1, 192 + w8);
        SCHEDBAR(); BAR();
        asm volatile("s_waitcnt lgkmcnt(0)"); SCHEDBAR();
        __builtin_amdgcn_s_setprio(1);
        mfma24(acc[0], a0, bf);
        __builtin_amdgcn_s_setprio(0);
        SCHEDBAR();
        asm volatile("s_waitcnt vmcnt(7)"); SCHEDBAR(); BAR();
        rd8(a1, smem, ab + arow + 4096, gs0, gs1);
        stA(T + 2, w8); stA(T + 2, 128 + w8);
        stB(T + 2, w8); stB(T + 2, 64 + w8); stB(T + 2, 128 + w8);
        SCHEDBAR(); BAR();
        asm volatile("s_waitcnt lgkmcnt(0)"); SCHEDBAR();
        __builtin_amdgcn_s_setprio(1);
        mfma24(acc[1], a1, bf);
        __builtin_amdgcn_s_setprio(0);
        SCHEDBAR();
        asm volatile("s_waitcnt vmcnt(7)"); SCHEDBAR(); BAR();
    }

    {
        const int ab = 0, bb = 32768;
        rd8(a0, smem, ab + arow, gs0, gs1);
        rd6(bf, smem, bb + brow, gs0, gs1);
        stA(17, 64 + w8); stA(17, 192 + w8);
        SCHEDBAR(); BAR();
        asm volatile("s_waitcnt lgkmcnt(0)"); SCHEDBAR();
        __builtin_amdgcn_s_setprio(1);
        mfma24(acc[0], a0, bf);
        __builtin_amdgcn_s_setprio(0);
        SCHEDBAR();
        asm volatile("s_waitcnt vmcnt(7)"); SCHEDBAR(); BAR();
        rd8(a1, smem, ab + arow + 4096, gs0, gs1);
        SCHEDBAR(); BAR();
        asm volatile("s_waitcnt lgkmcnt(0)"); SCHEDBAR();
        __builtin_amdgcn_s_setprio(1);
        mfma24(acc[1], a1, bf);
        __builtin_amdgcn_s_setprio(0);
        SCHEDBAR();
        asm volatile("s_waitcnt vmcnt(2)"); SCHEDBAR(); BAR();
    }
    {
        const int ab = 16384, bb = 32768 + 12288;
        rd8(a0, smem, ab + arow, gs0, gs1);
        rd6(bf, smem, bb + brow, gs0, gs1);
        SCHEDBAR(); BAR();
        asm volatile("s_waitcnt lgkmcnt(0)"); SCHEDBAR();
        __builtin_amdgcn_s_setprio(1);
        mfma24(acc[0], a0, bf);
        __builtin_amdgcn_s_setprio(0);
        SCHEDBAR();
        asm volatile("s_waitcnt vmcnt(0)"); SCHEDBAR(); BAR();
        rd8(a1, smem, ab + arow + 4096, gs0, gs1);
        SCHEDBAR();
        asm volatile("s_waitcnt lgkmcnt(0)"); SCHEDBAR();
        __builtin_amdgcn_s_setprio(1);
        mfma24(acc[1], a1, bf);
        __builtin_amdgcn_s_setprio(0);
        SCHEDBAR();
    }

#pragma unroll
    for (int h = 0; h < 2; ++h)
#pragma unroll
        for (int mi = 0; mi < 4; ++mi) {
            long row = rowBase + wm * 128 + (h * 4 + mi) * 16 + quad * 4;
#pragma unroll
            for (int ni = 0; ni < 3; ++ni) {
                int col = colBase + wn * 48 + ni * 16 + cl;
                float bv = bias[col];
#pragma unroll
                for (int r = 0; r < 4; ++r) {
                    float v = (acc[h][mi][ni][r] + bv) * scale;
                    if (MODE == 0) outA[(row + r) * 1152 + col] = f2bf(v);
                    else           outF[(row + r) * 1152L + col] = v;
                }
            }
        }
}

// ---------------- GEMM (m97 structure), small KV projection ----------------
// MODE 1: K -> outA [b][h][384][128] bf16, granule-XOR swizzled (pg = (dd>>3)^(mm&7)),
//         pads pre-zeroed (bijective swizzle => unwritten physical cells = logical pads);
//         V -> outB [b][h][3][72][128], m-granules XOR-swizzled by (dd&7)
template <int MODE>
__global__ __launch_bounds__(256)
void gemm_bt(const u16* __restrict__ A, const u16* __restrict__ Bt,
             const float* __restrict__ bias, float scale,
             u16* __restrict__ outA, u16* __restrict__ outB, float* __restrict__ outF,
             int M, int N, int K) {
    __shared__ u16 As[128 * 32];
    __shared__ u16 Bs[128 * 32];
    const int tid = threadIdx.x, lane = tid & 63, wave = tid >> 6;
    const int wm = wave >> 1, wn = wave & 1;
    const int quad = lane >> 4, cl = lane & 15;
    const long rowBase = (long)blockIdx.x * 128;
    const int colBase = blockIdx.y * 128;
    const int srow = lane >> 2;
    const int skc = (lane & 3) * 8;

    floatx4 acc[4][4];
#pragma unroll
    for (int i = 0; i < 4; i++)
#pragma unroll
        for (int j = 0; j < 4; j++) acc[i][j] = (floatx4){0.f, 0.f, 0.f, 0.f};

    for (int k0 = 0; k0 < K; k0 += 32) {
#pragma unroll
        for (int j = 0; j < 2; ++j) {
            int inst = wave * 2 + j;
            long r = rowBase + inst * 16 + srow;
            if (r > (long)M - 1) r = (long)M - 1;
            async16(A + r * K + k0 + skc, &As[inst * 512]);
        }
#pragma unroll
        for (int j = 0; j < 2; ++j) {
            int inst = wave * 2 + j;
            long r = colBase + inst * 16 + srow;
            async16(Bt + r * K + k0 + skc, &Bs[inst * 512]);
        }
        __syncthreads();
        short8 af[4], bfr[4];
#pragma unroll
        for (int mi = 0; mi < 4; mi++)
            af[mi] = *(const short8*)&As[(wm * 64 + mi * 16 + cl) * 32 + quad * 8];
#pragma unroll
        for (int ni = 0; ni < 4; ni++)
            bfr[ni] = *(const short8*)&Bs[(wn * 64 + ni * 16 + cl) * 32 + quad * 8];
#pragma unroll
        for (int mi = 0; mi < 4; mi++)
#pragma unroll
            for (int ni = 0; ni < 4; ni++)
                acc[mi][ni] = __builtin_amdgcn_mfma_f32_16x16x32_bf16(af[mi], bfr[ni], acc[mi][ni], 0, 0, 0);
        __syncthreads();
    }

#pragma unroll
    for (int mi = 0; mi < 4; mi++) {
        long row0 = rowBase + wm * 64 + mi * 16 + quad * 4;
#pragma unroll
        for (int ni = 0; ni < 4; ni++) {
            int col = colBase + wn * 64 + ni * 16 + cl;
            float bv = bias[col];
#pragma unroll
            for (int r = 0; r < 4; r++) {
                long row = row0 + r;
                if (row < M) {
                    float v = (acc[mi][ni][r] + bv) * scale;
                    if (MODE == 1) {
                        int bb = (int)(row / 300);
                        int mm = (int)(row - (long)bb * 300);
                        if (col < 1152) {
                            int hh = col / 72, dd = col - hh * 72;
                            int pg = (dd >> 3) ^ (mm & 7);
                            outA[((long)(bb * 16 + hh) * 384 + mm) * 128 + pg * 8 + (dd & 7)] = f2bf(v);
                        } else {
                            int c2 = col - 1152;
                            int hh = c2 / 72, dd = c2 - hh * 72;
                            int ch = mm >> 7, mc = mm & 127;
                            int g = (mc >> 3) ^ (dd & 7);
                            outB[(((long)(bb * 16 + hh) * 3 + ch) * 72 + dd) * 128 + g * 8 + (mc & 7)] = f2bf(v);
                        }
                    }
                }
            }
        }
    }
}

// ---------------- fused masked attention (R6: XOR-swizzled Ks/Ps, mask-skip, in-place O) ----------------
// grid (N/64, H=16, B=8), 256 threads (4 waves, 16 Q-rows each).
// Q [b][n][1152] bf16 -> registers; O written IN-PLACE over the same cells (block reads
// its own rows to regs at start, writes at end; no cross-block cell sharing).
// K [b][h][384][128] bf16 pre-swizzled (pg = (dd>>3)^(mm&7)), cols 72..127 logical-zero.
// V [b][h][3][72][128] bf16, m-granule swizzled by (dd&7).
// LDS: Ks [128][128] (32768 B, Ps [64][128]-swizzled aliases its low half), Vs [80][128]
// (20480 B) -> 53248 B -> 3 blocks/CU.
// All b128 LDS reads use the granule-XOR pattern (bank-balanced; 0 conflicts in gemm8p).
// Mask-skip (block-uniform): rem = mb - base, kklim = ceil(rem/32) (PV k-slots),
// tlim = 2*kklim (QK col-tiles, Ps tiles, Ks staging = 4*tlim loads). Exact: skipped
// P columns are identically zero.
__global__ __launch_bounds__(256, 3)
void attn_kernel(const u16* __restrict__ Q, const u16* __restrict__ K,
                 const u16* __restrict__ V, const int* __restrict__ mask,
                 u16* __restrict__ O) {
    __shared__ __align__(16) u16 smem[(32768 + 20480) / 2];
    u16* Ks = smem;                  // [128][128]; Ps alias: [64][128] swizzled
    u16* Vs = smem + 16384;          // [80][128]

    const int tid = threadIdx.x, lane = tid & 63, wave = tid >> 6;
    const int quad = lane >> 4, cl = lane & 15;
    const int b = blockIdx.z, h = blockIdx.y, nt = blockIdx.x;
    int mb = mask[b];
    if (mb > 300) mb = 300;
    if (mb < 1) mb = 1;
    const int bh = b * 16 + h;

    const long qbase = ((long)b * 4096 + nt * 64) * 1152 + h * 72;

    // Q fragments in registers: row = wave*16+cl; aq[2] real only for quad 0 (k 64..71).
    const u16* qrow = Q + qbase + (long)(wave * 16 + cl) * 1152;
    short8 zero8 = {0, 0, 0, 0, 0, 0, 0, 0};
    short8 aq[3];
    aq[0] = *(const short8*)(qrow + quad * 8);
    aq[1] = *(const short8*)(qrow + 32 + quad * 8);
    aq[2] = (quad == 0) ? *(const short8*)(qrow + 64) : zero8;

    // ones row dd=72 in Vs (staging covers rows 0..71 exactly)
    if (tid < 16) {
        unsigned fill = 0x3F803F80u;
        *(uint4*)&Vs[72 * 128 + tid * 8] = (uint4){fill, fill, fill, fill};
    }

    floatx4 oacc[5];
#pragma unroll
    for (int i = 0; i < 5; i++) oacc[i] = (floatx4){0.f, 0.f, 0.f, 0.f};

    const u16* kb = K + (long)bh * 384 * 128;
    const u16* vb = V + (long)bh * 3 * 9216;

    const int xr = (cl & 7);   // XOR key for this lane's LDS row (row&7 == cl&7)
    const int nch = (mb + 127) >> 7;
    for (int ch = 0; ch < nch; ++ch) {
        const int base = ch << 7;
        const int rem = mb - base;                       // >= 1
        const int kklim = (rem + 31) >> 5 > 4 ? 4 : (rem + 31) >> 5;
        const int tlim = kklim * 2;                      // QK col-tiles (16 keys each)
        __syncthreads();   // prev PV reads done; ones-row init visible (ch=0)

        // K chunk: 4*tlim loads of 1024 B (4 rows each), contiguous swizzled-global
        const u16* ksrc = kb + (long)base * 128;
        for (int i = wave; i < 4 * tlim; i += 4)
            async16(ksrc + i * 512 + lane * 8, Ks + i * 512);
        // V chunk: 72 rows x 256 B = 18432 B contiguous (pre-swizzled source)
        const u16* vsrc = vb + (long)ch * 9216;
        for (int i = wave; i < 18; i += 4)
            async16(vsrc + i * 512 + lane * 8, Vs + i * 512);
        __syncthreads();   // staging complete

        // S = Q @ K^T : tlim col-tiles, 3 k-iters over padded d=96 (cols 72..95 zero)
        floatx4 sacc[8];
#pragma unroll
        for (int t = 0; t < 8; t++) sacc[t] = (floatx4){0.f, 0.f, 0.f, 0.f};
        for (int kk = 0; kk < 3; ++kk) {
            const int pg = ((kk * 4 + quad) ^ xr) * 8;
            for (int t = 0; t < tlim; ++t) {
                short8 bfr = *(const short8*)&Ks[(t * 16 + cl) * 128 + pg];
                sacc[t] = __builtin_amdgcn_mfma_f32_16x16x32_bf16(aq[kk], bfr, sacc[t], 0, 0, 0);
            }
        }
        __syncthreads();   // all waves done reading Ks before Ps overwrite

        // p = exp(s), masked -> 0; pack col-pairs via cvt_pk; swizzled b32 writes.
#pragma unroll
        for (int r = 0; r < 4; ++r) {
            int prow = wave * 16 + quad * 4 + r;
            int pb8 = prow * 128 + (cl & 6);     // within-granule offset (even)
            int rk = (prow & 7);
            for (int t = 0; t < tlim; ++t) {
                int col = base + t * 16 + cl;
                float p = (col < mb) ? __expf(sacc[t][r]) : 0.f;
                float po = __shfl_xor(p, 1);
                if (!(lane & 1)) {
                    unsigned pk;
                    asm("v_cvt_pk_bf16_f32 %0, %1, %2" : "=v"(pk) : "v"(p), "v"(po));
                    int pg = ((t * 2 + (cl >> 3)) ^ rk) * 8;
                    *(unsigned*)&Ks[pb8 + pg] = pk;
                }
            }
        }
        // no barrier: each wave reads only its own 16 Ps rows below

        // O += P @ V : 5 dd-tiles (incl. ones-row sum), kklim k-iters over m
        for (int kk = 0; kk < kklim; ++kk) {
            short8 pf = *(const short8*)&Ks[(wave * 16 + cl) * 128 + ((kk * 4 + quad) ^ xr) * 8];
#pragma unroll
            for (int dt = 0; dt < 5; ++dt) {
                int dd = dt * 16 + cl;
                short8 vf = *(const short8*)&Vs[dd * 128 + (((kk * 4 + quad) ^ (dd & 7)) << 3)];
                oacc[dt] = __builtin_amdgcn_mfma_f32_16x16x32_bf16(pf, vf, oacc[dt], 0, 0, 0);
            }
        }
    }

    // epilogue: l = oacc[4] at cl==8 (ones column, dd=72); broadcast within quad
#pragma unroll
    for (int r = 0; r < 4; r++) {
        float l = __shfl(oacc[4][r], (lane & 48) + 8);
        float inv = 1.0f / l;
        int row = wave * 16 + quad * 4 + r;
#pragma unroll
        for (int dt = 0; dt < 5; dt++) {
            int dd = dt * 16 + cl;
            if (dd < 72) O[qbase + (long)row * 1152 + dd] = f2bf(oacc[dt][r] * inv);
        }
    }
}

extern "C" void kernel_launch(void* const* d_in, const int* in_sizes, int n_in,
                              void* d_out, int out_size, void* d_ws, size_t ws_size,
                              hipStream_t stream) {
    const float* x    = (const float*)d_in[0];
    const float* cond = (const float*)d_in[1];
    const int*   mask = (const int*)d_in[2];
    const float* wq   = (const float*)d_in[3];
    const float* bq   = (const float*)d_in[4];
    const float* wkv  = (const float*)d_in[5];
    const float* bkv  = (const float*)d_in[6];
    const float* wp   = (const float*)d_in[7];
    const float* bp   = (const float*)d_in[8];

    char* ws = (char*)d_ws;
    // Layout (time-multiplexed):
    //  [0, 75.5MB)      xb: x bf16 (cast -> Q-proj). After Q-proj DEAD; head reused:
    //                     kswz [b][h][384][128] swizzled (12,582,912) at +0
    //                     vbuf [b][h][3][72][128]          (7,077,888) at +12,582,912
    //  [75.5, 151MB)    qbuf: Q bf16 (Q-proj -> attn); attn writes O IN-PLACE; P-proj reads.
    //  [151, 156.5MB)   condb (5,529,600)
    //  [156.5, 161.8MB) wkvT  (5,308,416)
    //  [161.8, 164.5MB) wqT / wpT (2,654,208; time-disjoint)
    u16* xb    = (u16*)(ws);
    u16* kswz  = (u16*)(ws);
    u16* vbuf  = (u16*)(ws + 12582912ll);
    u16* qbuf  = (u16*)(ws + 75497472ll);
    u16* condb = (u16*)(ws + 150994944ll);
    u16* wkvT  = (u16*)(ws + 156524544ll);
    u16* wqT   = (u16*)(ws + 161832960ll);
    u16* wpT   = (u16*)(ws + 161832960ll);
    if (ws_size < 175988736ull) return;

    static bool s_attr = false;
    if (!s_attr) {
        hipFuncSetAttribute((const void*)gemm8p<0>, hipFuncAttributeMaxDynamicSharedMemorySize, 114688);
        hipFuncSetAttribute((const void*)gemm8p<2>, hipFuncAttributeMaxDynamicSharedMemorySize, 114688);
        s_attr = true;
    }

    cast_bf16_kernel<<<18432, 256, 0, stream>>>(x, xb, 4718592ll);
    cast_bf16_kernel<<<1350, 256, 0, stream>>>(cond, condb, 345600ll);

    transpose_cast<<<dim3(36, 36), dim3(32, 8), 0, stream>>>(wq, wqT, 1152, 1152);
    transpose_cast<<<dim3(72, 36), dim3(32, 8), 0, stream>>>(wkv, wkvT, 1152, 2304);

    // Q = (x@wq + bq) * 1/sqrt(72), bf16 -> qbuf (xb fully consumed here)
    gemm8p<0><<<768, 512, 114688, stream>>>(xb, wqT, bq, 0.11785113019775793f, qbuf, nullptr);

    // zero kswz+vbuf (19,660,800 B, aliases dead xb head)
    fill_zero<<<4800, 256, 0, stream>>>((uint4*)kswz, 1228800);
    // KV = cond@wkv + bkv -> K swizzled-padded / V chunk-swizzled, bf16
    gemm_bt<1><<<dim3(19, 18), 256, 0, stream>>>(condb, wkvT, bkv, 1.0f,
                                                 kswz, vbuf, nullptr, 2400, 2304, 1152);
    // attention: reads Q from qbuf, writes O in-place over qbuf
    attn_kernel<<<dim3(64, 16, 8), 256, 0, stream>>>(qbuf, kswz, vbuf, mask, qbuf);

    transpose_cast<<<dim3(36, 36), dim3(32, 8), 0, stream>>>(wp, wpT, 1152, 1152);
    // out = attn@wp + bp, fp32
    gemm8p<2><<<768, 512, 114688, stream>>>(qbuf, wpT, bp, 1.0f, nullptr, (float*)d_out);
}